// Round 1
// baseline (3497.368 us; speedup 1.0000x reference)
//
#include <hip/hip_runtime.h>
#include <math.h>

#define EMB 1024
#define HEADS 16
#define HDIM 64
#define NBATCH 4
#define SEQ 2048
#define ROWS (NBATCH * SEQ)   // 8192
#define SCALE 0.125f          // 64^-0.5

// ---------------- LayerNorm: one block (256 thr) per row of 1024 ----------------
__global__ __launch_bounds__(256) void ln_kernel(const float* __restrict__ x,
                                                 const float* __restrict__ w,
                                                 const float* __restrict__ b,
                                                 float* __restrict__ h) {
    int row = blockIdx.x;
    const float* xr = x + (size_t)row * EMB;
    float* hr = h + (size_t)row * EMB;
    float4 v = ((const float4*)xr)[threadIdx.x];        // 256*4 = 1024
    float s  = v.x + v.y + v.z + v.w;
    float ss = v.x*v.x + v.y*v.y + v.z*v.z + v.w*v.w;
    #pragma unroll
    for (int o = 32; o; o >>= 1) { s += __shfl_xor(s, o); ss += __shfl_xor(ss, o); }
    __shared__ float red[8];
    int wid = threadIdx.x >> 6;
    if ((threadIdx.x & 63) == 0) { red[wid] = s; red[4 + wid] = ss; }
    __syncthreads();
    if (threadIdx.x == 0) {
        red[0] = red[0] + red[1] + red[2] + red[3];
        red[4] = red[4] + red[5] + red[6] + red[7];
    }
    __syncthreads();
    float mu  = red[0] * (1.f / EMB);
    float var = red[4] * (1.f / EMB) - mu * mu;
    float rstd = rsqrtf(var + 1e-5f);
    float4 wv = ((const float4*)w)[threadIdx.x];
    float4 bv = ((const float4*)b)[threadIdx.x];
    float4 o;
    o.x = (v.x - mu) * rstd * wv.x + bv.x;
    o.y = (v.y - mu) * rstd * wv.y + bv.y;
    o.z = (v.z - mu) * rstd * wv.z + bv.z;
    o.w = (v.w - mu) * rstd * wv.w + bv.w;
    ((float4*)hr)[threadIdx.x] = o;
}

// ---------------- QKV GEMM: h[8192,1024] @ w_qkv[1024,3072] + b -> scatter q/k/v ----------------
// 64x64 tile, BK=16, 256 threads, 4x4 microtile per thread.
__global__ __launch_bounds__(256) void qkv_gemm(const float* __restrict__ A,
                                                const float* __restrict__ B,
                                                const float* __restrict__ bias,
                                                float* __restrict__ qo,
                                                float* __restrict__ ko,
                                                float* __restrict__ vo) {
    const int N = 3 * EMB;  // 3072
    __shared__ float As[16][64];
    __shared__ float Bs[16][64];
    int tid = threadIdx.x;
    int bm = blockIdx.y, bn = blockIdx.x;
    int ty = tid >> 4, tx = tid & 15;
    int arow = tid >> 2;            // 0..63
    int acol4 = (tid & 3) * 4;      // 0,4,8,12
    int brow = tid >> 4;            // 0..15
    int bcol4 = (tid & 15) * 4;     // 0..60
    const float* Ap = A + ((size_t)bm * 64 + arow) * EMB + acol4;
    const float* Bp = B + (size_t)brow * N + bn * 64 + bcol4;
    float acc[4][4] = {};
    for (int k0 = 0; k0 < EMB; k0 += 16) {
        float4 av = *(const float4*)(Ap + k0);
        float4 bv = *(const float4*)(Bp + (size_t)k0 * N);
        __syncthreads();
        As[acol4 + 0][arow] = av.x;
        As[acol4 + 1][arow] = av.y;
        As[acol4 + 2][arow] = av.z;
        As[acol4 + 3][arow] = av.w;
        *(float4*)&Bs[brow][bcol4] = bv;
        __syncthreads();
        #pragma unroll
        for (int kk = 0; kk < 16; ++kk) {
            float a[4], bb[4];
            #pragma unroll
            for (int i = 0; i < 4; ++i) a[i] = As[kk][ty * 4 + i];
            #pragma unroll
            for (int j = 0; j < 4; ++j) bb[j] = Bs[kk][tx * 4 + j];
            #pragma unroll
            for (int i = 0; i < 4; ++i)
                #pragma unroll
                for (int j = 0; j < 4; ++j) acc[i][j] += a[i] * bb[j];
        }
    }
    // epilogue: add bias, de-interleave qkv, write [b][head][n][d]
    #pragma unroll
    for (int i = 0; i < 4; ++i) {
        int row = bm * 64 + ty * 4 + i;
        int bb = row >> 11;          // /2048
        int nq = row & 2047;
        #pragma unroll
        for (int j = 0; j < 4; ++j) {
            int c = bn * 64 + tx * 4 + j;
            float val = acc[i][j] + bias[c];
            int head = c / 192;
            int rem = c - head * 192;
            int d = rem / 3;
            int which = rem - d * 3;
            float* dst = which == 0 ? qo : (which == 1 ? ko : vo);
            dst[(((size_t)bb * HEADS + head) * SEQ + nq) * HDIM + d] = val;
        }
    }
}

// ---------------- Flash attention: block per (b, head, 64-query tile) ----------------
// 256 threads: thread t -> query qi=t>>2, sub=t&3. Scores: sub = 16-j group;
// PV: sub = 16-dim group. K/V tiles in padded LDS; q row in registers.
__global__ __launch_bounds__(256) void attn_kernel(const float* __restrict__ Q,
                                                   const float* __restrict__ K,
                                                   const float* __restrict__ V,
                                                   float* __restrict__ O) {
    __shared__ float ks[64][68];
    __shared__ float vs[64][68];
    __shared__ float ps[64][66];
    int tid = threadIdx.x;
    int qi = tid >> 2;
    int sub = tid & 3;
    int b = blockIdx.z, hh = blockIdx.y;
    int q0 = blockIdx.x * 64;
    size_t bh = ((size_t)b * HEADS + hh) * SEQ * HDIM;
    const float* qp = Q + bh + (size_t)(q0 + qi) * HDIM;
    float4 qreg[16];
    #pragma unroll
    for (int t = 0; t < 16; ++t) qreg[t] = ((const float4*)qp)[t];
    float4 acc4[4];
    #pragma unroll
    for (int t = 0; t < 4; ++t) acc4[t] = make_float4(0.f, 0.f, 0.f, 0.f);
    float m = -INFINITY, l = 0.f;
    const float* kbase = K + bh;
    const float* vbase = V + bh;
    for (int kb = 0; kb < SEQ / 64; ++kb) {
        __syncthreads();
        const float* kp = kbase + (size_t)kb * 64 * HDIM;
        const float* vp = vbase + (size_t)kb * 64 * HDIM;
        #pragma unroll
        for (int i = 0; i < 4; ++i) {
            int f = tid + i * 256;
            int r = f >> 4, c4 = (f & 15) * 4;
            *(float4*)&ks[r][c4] = *(const float4*)(kp + r * HDIM + c4);
            *(float4*)&vs[r][c4] = *(const float4*)(vp + r * HDIM + c4);
        }
        __syncthreads();
        float s[16];
        #pragma unroll
        for (int jj = 0; jj < 16; ++jj) {
            int j = (sub << 4) + jj;
            float d0 = 0.f;
            #pragma unroll
            for (int t = 0; t < 16; ++t) {
                float4 kv = *(const float4*)&ks[j][t * 4];
                d0 += qreg[t].x * kv.x + qreg[t].y * kv.y
                    + qreg[t].z * kv.z + qreg[t].w * kv.w;
            }
            s[jj] = d0 * SCALE;
        }
        float mx = s[0];
        #pragma unroll
        for (int jj = 1; jj < 16; ++jj) mx = fmaxf(mx, s[jj]);
        mx = fmaxf(mx, __shfl_xor(mx, 1));
        mx = fmaxf(mx, __shfl_xor(mx, 2));
        float mnew = fmaxf(m, mx);
        float pscale = __expf(m - mnew);
        float lsum = 0.f;
        #pragma unroll
        for (int jj = 0; jj < 16; ++jj) {
            float p = __expf(s[jj] - mnew);
            ps[qi][(sub << 4) + jj] = p;
            lsum += p;
        }
        lsum += __shfl_xor(lsum, 1);
        lsum += __shfl_xor(lsum, 2);
        l = l * pscale + lsum;
        m = mnew;
        #pragma unroll
        for (int t = 0; t < 4; ++t) {
            acc4[t].x *= pscale; acc4[t].y *= pscale;
            acc4[t].z *= pscale; acc4[t].w *= pscale;
        }
        __syncthreads();
        for (int j = 0; j < 64; ++j) {
            float p = ps[qi][j];
            #pragma unroll
            for (int t = 0; t < 4; ++t) {
                float4 vv = *(const float4*)&vs[j][(sub << 4) + t * 4];
                acc4[t].x += p * vv.x; acc4[t].y += p * vv.y;
                acc4[t].z += p * vv.z; acc4[t].w += p * vv.w;
            }
        }
    }
    float inv = 1.f / l;
    float* op = O + ((size_t)b * SEQ + q0 + qi) * EMB + hh * HDIM + (sub << 4);
    #pragma unroll
    for (int t = 0; t < 4; ++t) {
        float4 o = make_float4(acc4[t].x * inv, acc4[t].y * inv,
                               acc4[t].z * inv, acc4[t].w * inv);
        ((float4*)op)[t] = o;
    }
}

// ---------------- Proj GEMM: att[8192,1024] @ w_proj[1024,1024] + b + residual ----------------
__global__ __launch_bounds__(256) void proj_gemm(const float* __restrict__ A,
                                                 const float* __restrict__ B,
                                                 const float* __restrict__ bias,
                                                 const float* __restrict__ resid,
                                                 float* __restrict__ out) {
    const int N = EMB;  // 1024
    __shared__ float As[16][64];
    __shared__ float Bs[16][64];
    int tid = threadIdx.x;
    int bm = blockIdx.y, bn = blockIdx.x;
    int ty = tid >> 4, tx = tid & 15;
    int arow = tid >> 2;
    int acol4 = (tid & 3) * 4;
    int brow = tid >> 4;
    int bcol4 = (tid & 15) * 4;
    const float* Ap = A + ((size_t)bm * 64 + arow) * EMB + acol4;
    const float* Bp = B + (size_t)brow * N + bn * 64 + bcol4;
    float acc[4][4] = {};
    for (int k0 = 0; k0 < EMB; k0 += 16) {
        float4 av = *(const float4*)(Ap + k0);
        float4 bv = *(const float4*)(Bp + (size_t)k0 * N);
        __syncthreads();
        As[acol4 + 0][arow] = av.x;
        As[acol4 + 1][arow] = av.y;
        As[acol4 + 2][arow] = av.z;
        As[acol4 + 3][arow] = av.w;
        *(float4*)&Bs[brow][bcol4] = bv;
        __syncthreads();
        #pragma unroll
        for (int kk = 0; kk < 16; ++kk) {
            float a[4], bb[4];
            #pragma unroll
            for (int i = 0; i < 4; ++i) a[i] = As[kk][ty * 4 + i];
            #pragma unroll
            for (int j = 0; j < 4; ++j) bb[j] = Bs[kk][tx * 4 + j];
            #pragma unroll
            for (int i = 0; i < 4; ++i)
                #pragma unroll
                for (int j = 0; j < 4; ++j) acc[i][j] += a[i] * bb[j];
        }
    }
    #pragma unroll
    for (int i = 0; i < 4; ++i) {
        size_t row = (size_t)bm * 64 + ty * 4 + i;
        #pragma unroll
        for (int j = 0; j < 4; ++j) {
            int c = bn * 64 + tx * 4 + j;
            out[row * EMB + c] = acc[i][j] + bias[c] + resid[row * EMB + c];
        }
    }
}

extern "C" void kernel_launch(void* const* d_in, const int* in_sizes, int n_in,
                              void* d_out, int out_size, void* d_ws, size_t ws_size,
                              hipStream_t stream) {
    const float* x      = (const float*)d_in[0];
    const float* ln_w   = (const float*)d_in[1];
    const float* ln_b   = (const float*)d_in[2];
    const float* w_qkv  = (const float*)d_in[3];
    const float* b_qkv  = (const float*)d_in[4];
    const float* w_proj = (const float*)d_in[5];
    const float* b_proj = (const float*)d_in[6];
    float* out = (float*)d_out;

    char* ws = (char*)d_ws;
    const size_t MB32 = (size_t)ROWS * EMB * sizeof(float);  // 32 MiB
    float* h = (float*)ws;                    // normalized x; later reused as attn out
    float* q = (float*)(ws + MB32);
    float* k = (float*)(ws + 2 * MB32);
    float* v = (float*)(ws + 3 * MB32);

    ln_kernel<<<ROWS, 256, 0, stream>>>(x, ln_w, ln_b, h);
    qkv_gemm<<<dim3(48, 128), 256, 0, stream>>>(h, w_qkv, b_qkv, q, k, v);
    attn_kernel<<<dim3(SEQ / 64, HEADS, NBATCH), 256, 0, stream>>>(q, k, v, h);
    proj_gemm<<<dim3(16, 128), 256, 0, stream>>>(h, w_proj, b_proj, x, out);
}

// Round 3
// 1221.263 us; speedup vs baseline: 2.8637x; 2.8637x over previous
//
#include <hip/hip_runtime.h>
#include <math.h>

#define EMB 1024
#define HEADS 16
#define HDIM 64
#define NBATCH 4
#define SEQ 2048
#define ROWS (NBATCH * SEQ)   // 8192
#define SCALE 0.125f          // 64^-0.5

typedef float f32x4 __attribute__((ext_vector_type(4)));
typedef short bf16x8 __attribute__((ext_vector_type(8)));

__device__ inline unsigned short f2bf(float f) {
    unsigned int u = __builtin_bit_cast(unsigned int, f);
    u += 0x7fffu + ((u >> 16) & 1u);   // round-to-nearest-even
    return (unsigned short)(u >> 16);
}

// ---------------- LayerNorm: one block (256 thr) per row of 1024 ----------------
__global__ __launch_bounds__(256) void ln_kernel(const float* __restrict__ x,
                                                 const float* __restrict__ w,
                                                 const float* __restrict__ b,
                                                 float* __restrict__ h) {
    int row = blockIdx.x;
    const float* xr = x + (size_t)row * EMB;
    float* hr = h + (size_t)row * EMB;
    float4 v = ((const float4*)xr)[threadIdx.x];
    float s  = v.x + v.y + v.z + v.w;
    float ss = v.x*v.x + v.y*v.y + v.z*v.z + v.w*v.w;
    #pragma unroll
    for (int o = 32; o; o >>= 1) { s += __shfl_xor(s, o); ss += __shfl_xor(ss, o); }
    __shared__ float red[8];
    int wid = threadIdx.x >> 6;
    if ((threadIdx.x & 63) == 0) { red[wid] = s; red[4 + wid] = ss; }
    __syncthreads();
    if (threadIdx.x == 0) {
        red[0] = red[0] + red[1] + red[2] + red[3];
        red[4] = red[4] + red[5] + red[6] + red[7];
    }
    __syncthreads();
    float mu  = red[0] * (1.f / EMB);
    float var = red[4] * (1.f / EMB) - mu * mu;
    float rstd = rsqrtf(var + 1e-5f);
    float4 wv = ((const float4*)w)[threadIdx.x];
    float4 bv = ((const float4*)b)[threadIdx.x];
    float4 o;
    o.x = (v.x - mu) * rstd * wv.x + bv.x;
    o.y = (v.y - mu) * rstd * wv.y + bv.y;
    o.z = (v.z - mu) * rstd * wv.z + bv.z;
    o.w = (v.w - mu) * rstd * wv.w + bv.w;
    ((float4*)hr)[threadIdx.x] = o;
}

// ---------------- QKV GEMM (f32 compute) -> bf16 q/k/v; v pre-transposed ----------------
// q,k: [b][h][n][d] bf16.  v: [b][h][d][n] bf16 (transposed for attention PV).
__global__ __launch_bounds__(256) void qkv_gemm(const float* __restrict__ A,
                                                const float* __restrict__ B,
                                                const float* __restrict__ bias,
                                                unsigned short* __restrict__ qo,
                                                unsigned short* __restrict__ ko,
                                                unsigned short* __restrict__ vo) {
    const int N = 3 * EMB;  // 3072
    __shared__ float As[16][64];
    __shared__ float Bs[16][64];
    int tid = threadIdx.x;
    int bm = blockIdx.y, bn = blockIdx.x;
    int ty = tid >> 4, tx = tid & 15;
    int arow = tid >> 2;
    int acol4 = (tid & 3) * 4;
    int brow = tid >> 4;
    int bcol4 = (tid & 15) * 4;
    const float* Ap = A + ((size_t)bm * 64 + arow) * EMB + acol4;
    const float* Bp = B + (size_t)brow * N + bn * 64 + bcol4;
    float acc[4][4] = {};
    for (int k0 = 0; k0 < EMB; k0 += 16) {
        float4 av = *(const float4*)(Ap + k0);
        float4 bv = *(const float4*)(Bp + (size_t)k0 * N);
        __syncthreads();
        As[acol4 + 0][arow] = av.x;
        As[acol4 + 1][arow] = av.y;
        As[acol4 + 2][arow] = av.z;
        As[acol4 + 3][arow] = av.w;
        *(float4*)&Bs[brow][bcol4] = bv;
        __syncthreads();
        #pragma unroll
        for (int kk = 0; kk < 16; ++kk) {
            float a[4], bb[4];
            #pragma unroll
            for (int i = 0; i < 4; ++i) a[i] = As[kk][ty * 4 + i];
            #pragma unroll
            for (int j = 0; j < 4; ++j) bb[j] = Bs[kk][tx * 4 + j];
            #pragma unroll
            for (int i = 0; i < 4; ++i)
                #pragma unroll
                for (int j = 0; j < 4; ++j) acc[i][j] += a[i] * bb[j];
        }
    }
    #pragma unroll
    for (int i = 0; i < 4; ++i) {
        int row = bm * 64 + ty * 4 + i;
        int bb = row >> 11;          // /2048
        int nq = row & 2047;
        #pragma unroll
        for (int j = 0; j < 4; ++j) {
            int c = bn * 64 + tx * 4 + j;
            float val = acc[i][j] + bias[c];
            int head = c / 192;
            int rem = c - head * 192;
            int d = rem / 3;
            int which = rem - d * 3;
            unsigned short hv = f2bf(val);
            if (which == 0)
                qo[(((size_t)bb * HEADS + head) * SEQ + nq) * HDIM + d] = hv;
            else if (which == 1)
                ko[(((size_t)bb * HEADS + head) * SEQ + nq) * HDIM + d] = hv;
            else
                vo[(((size_t)bb * HEADS + head) * HDIM + d) * SEQ + nq] = hv;
        }
    }
}

// ---------------- Flash attention, bf16 MFMA 16x16x32 ----------------
// Block: 4 waves, 64-query tile (16 q/wave). KVBLK=64 staged in padded LDS.
// QK^T: A=Q frag (hoisted), B=K rows from LDS. Softmax f32 in C-layout.
// P -> bf16 via per-wave LDS round trip (C-layout write, A-layout b128 read).
// PV: B=V^T rows from LDS (V pre-transposed in global).
__global__ __launch_bounds__(256) void attn_mfma(const unsigned short* __restrict__ Q,
                                                 const unsigned short* __restrict__ K,
                                                 const unsigned short* __restrict__ VT,
                                                 float* __restrict__ O) {
    __shared__ unsigned short ks[64][72];   // [key][d]  +8 pad: row=144B -> 2-way max
    __shared__ unsigned short vt[64][72];   // [d][key]
    __shared__ unsigned short ps[4][16][72];// per-wave P tile [q][key]
    int tid = threadIdx.x;
    int w = tid >> 6, lane = tid & 63;
    int lg = lane >> 4, lr = lane & 15;
    int b = blockIdx.z, hh = blockIdx.y;
    int q0 = blockIdx.x * 64;
    size_t bh = ((size_t)b * HEADS + hh) * (size_t)SEQ * HDIM;
    // Q A-frags: lane holds row (lane&15), k = 8*(lane>>4)+j (+32 for second MFMA)
    const unsigned short* qg = Q + bh + (size_t)(q0 + w * 16 + lr) * HDIM + 8 * lg;
    bf16x8 qf0 = *(const bf16x8*)qg;
    bf16x8 qf1 = *(const bf16x8*)(qg + 32);
    f32x4 o[4];
    #pragma unroll
    for (int dt = 0; dt < 4; ++dt) o[dt] = (f32x4){0.f, 0.f, 0.f, 0.f};
    float m[4] = {-INFINITY, -INFINITY, -INFINITY, -INFINITY};
    float l[4] = {0.f, 0.f, 0.f, 0.f};
    const unsigned short* kg = K + bh;
    const unsigned short* vg = VT + bh;            // [64][SEQ]
    int sr = tid >> 2;                             // staging row 0..63
    int sc = (tid & 3) << 4;                       // staging col 0,16,32,48
    for (int kb = 0; kb < SEQ / 64; ++kb) {
        __syncthreads();
        const unsigned short* kp = kg + (size_t)(kb * 64 + sr) * HDIM + sc;
        *(float4*)&ks[sr][sc]     = *(const float4*)kp;
        *(float4*)&ks[sr][sc + 8] = *(const float4*)(kp + 8);
        const unsigned short* vp = vg + (size_t)sr * SEQ + kb * 64 + sc;
        *(float4*)&vt[sr][sc]     = *(const float4*)vp;
        *(float4*)&vt[sr][sc + 8] = *(const float4*)(vp + 8);
        __syncthreads();
        // ---- QK^T: S[16q][64k] per wave, 8 MFMAs ----
        f32x4 s[4];
        #pragma unroll
        for (int kn = 0; kn < 4; ++kn) {
            bf16x8 kf0 = *(const bf16x8*)&ks[kn * 16 + lr][8 * lg];
            bf16x8 kf1 = *(const bf16x8*)&ks[kn * 16 + lr][32 + 8 * lg];
            f32x4 acc = (f32x4){0.f, 0.f, 0.f, 0.f};
            acc = __builtin_amdgcn_mfma_f32_16x16x32_bf16(qf0, kf0, acc, 0, 0, 0);
            acc = __builtin_amdgcn_mfma_f32_16x16x32_bf16(qf1, kf1, acc, 0, 0, 0);
            s[kn] = acc;
        }
        // ---- online softmax (rows = (lane>>4)*4 + r; reduce over 16-lane group) ----
        #pragma unroll
        for (int r = 0; r < 4; ++r) {
            float s0 = s[0][r] * SCALE, s1 = s[1][r] * SCALE;
            float s2 = s[2][r] * SCALE, s3 = s[3][r] * SCALE;
            float mr = fmaxf(fmaxf(s0, s1), fmaxf(s2, s3));
            mr = fmaxf(mr, __shfl_xor(mr, 1));
            mr = fmaxf(mr, __shfl_xor(mr, 2));
            mr = fmaxf(mr, __shfl_xor(mr, 4));
            mr = fmaxf(mr, __shfl_xor(mr, 8));
            float mn = fmaxf(m[r], mr);
            float cr = __expf(m[r] - mn);
            float p0 = __expf(s0 - mn), p1 = __expf(s1 - mn);
            float p2 = __expf(s2 - mn), p3 = __expf(s3 - mn);
            float ls = p0 + p1 + p2 + p3;
            ls += __shfl_xor(ls, 1);
            ls += __shfl_xor(ls, 2);
            ls += __shfl_xor(ls, 4);
            ls += __shfl_xor(ls, 8);
            l[r] = l[r] * cr + ls;
            m[r] = mn;
            int q = lg * 4 + r;
            ps[w][q][lr]      = f2bf(p0);
            ps[w][q][lr + 16] = f2bf(p1);
            ps[w][q][lr + 32] = f2bf(p2);
            ps[w][q][lr + 48] = f2bf(p3);
            #pragma unroll
            for (int dt = 0; dt < 4; ++dt) o[dt][r] *= cr;
        }
        // ---- PV: O[16q][64d] += P[16q][64k] @ V[64k][64d], 8 MFMAs ----
        bf16x8 pa0 = *(const bf16x8*)&ps[w][lr][8 * lg];
        bf16x8 pa1 = *(const bf16x8*)&ps[w][lr][32 + 8 * lg];
        #pragma unroll
        for (int dt = 0; dt < 4; ++dt) {
            bf16x8 vf0 = *(const bf16x8*)&vt[dt * 16 + lr][8 * lg];
            bf16x8 vf1 = *(const bf16x8*)&vt[dt * 16 + lr][32 + 8 * lg];
            o[dt] = __builtin_amdgcn_mfma_f32_16x16x32_bf16(pa0, vf0, o[dt], 0, 0, 0);
            o[dt] = __builtin_amdgcn_mfma_f32_16x16x32_bf16(pa1, vf1, o[dt], 0, 0, 0);
        }
    }
    #pragma unroll
    for (int r = 0; r < 4; ++r) {
        float inv = 1.f / l[r];
        int q = q0 + w * 16 + lg * 4 + r;
        float* op = O + ((size_t)b * SEQ + q) * EMB + hh * HDIM + lr;
        #pragma unroll
        for (int dt = 0; dt < 4; ++dt) op[dt * 16] = o[dt][r] * inv;
    }
}

// ---------------- Proj GEMM: att[8192,1024] @ w_proj[1024,1024] + b + residual ----------------
__global__ __launch_bounds__(256) void proj_gemm(const float* __restrict__ A,
                                                 const float* __restrict__ B,
                                                 const float* __restrict__ bias,
                                                 const float* __restrict__ resid,
                                                 float* __restrict__ out) {
    const int N = EMB;
    __shared__ float As[16][64];
    __shared__ float Bs[16][64];
    int tid = threadIdx.x;
    int bm = blockIdx.y, bn = blockIdx.x;
    int ty = tid >> 4, tx = tid & 15;
    int arow = tid >> 2;
    int acol4 = (tid & 3) * 4;
    int brow = tid >> 4;
    int bcol4 = (tid & 15) * 4;
    const float* Ap = A + ((size_t)bm * 64 + arow) * EMB + acol4;
    const float* Bp = B + (size_t)brow * N + bn * 64 + bcol4;
    float acc[4][4] = {};
    for (int k0 = 0; k0 < EMB; k0 += 16) {
        float4 av = *(const float4*)(Ap + k0);
        float4 bv = *(const float4*)(Bp + (size_t)k0 * N);
        __syncthreads();
        As[acol4 + 0][arow] = av.x;
        As[acol4 + 1][arow] = av.y;
        As[acol4 + 2][arow] = av.z;
        As[acol4 + 3][arow] = av.w;
        *(float4*)&Bs[brow][bcol4] = bv;
        __syncthreads();
        #pragma unroll
        for (int kk = 0; kk < 16; ++kk) {
            float a[4], bb[4];
            #pragma unroll
            for (int i = 0; i < 4; ++i) a[i] = As[kk][ty * 4 + i];
            #pragma unroll
            for (int j = 0; j < 4; ++j) bb[j] = Bs[kk][tx * 4 + j];
            #pragma unroll
            for (int i = 0; i < 4; ++i)
                #pragma unroll
                for (int j = 0; j < 4; ++j) acc[i][j] += a[i] * bb[j];
        }
    }
    #pragma unroll
    for (int i = 0; i < 4; ++i) {
        size_t row = (size_t)bm * 64 + ty * 4 + i;
        #pragma unroll
        for (int j = 0; j < 4; ++j) {
            int c = bn * 64 + tx * 4 + j;
            out[row * EMB + c] = acc[i][j] + bias[c] + resid[row * EMB + c];
        }
    }
}

extern "C" void kernel_launch(void* const* d_in, const int* in_sizes, int n_in,
                              void* d_out, int out_size, void* d_ws, size_t ws_size,
                              hipStream_t stream) {
    const float* x      = (const float*)d_in[0];
    const float* ln_w   = (const float*)d_in[1];
    const float* ln_b   = (const float*)d_in[2];
    const float* w_qkv  = (const float*)d_in[3];
    const float* b_qkv  = (const float*)d_in[4];
    const float* w_proj = (const float*)d_in[5];
    const float* b_proj = (const float*)d_in[6];
    float* out = (float*)d_out;

    char* ws = (char*)d_ws;
    const size_t MB32 = (size_t)ROWS * EMB * sizeof(float);          // 32 MiB
    const size_t MB16 = (size_t)ROWS * EMB * sizeof(unsigned short); // 16 MiB
    float* h = (float*)ws;                               // LN out; reused as attn out
    unsigned short* q = (unsigned short*)(ws + MB32);
    unsigned short* k = (unsigned short*)(ws + MB32 + MB16);
    unsigned short* v = (unsigned short*)(ws + MB32 + 2 * MB16);

    ln_kernel<<<ROWS, 256, 0, stream>>>(x, ln_w, ln_b, h);
    qkv_gemm<<<dim3(48, 128), 256, 0, stream>>>(h, w_qkv, b_qkv, q, k, v);
    attn_mfma<<<dim3(SEQ / 64, HEADS, NBATCH), 256, 0, stream>>>(q, k, v, h);
    proj_gemm<<<dim3(16, 128), 256, 0, stream>>>(h, w_proj, b_proj, x, out);
}

// Round 4
// 371.021 us; speedup vs baseline: 9.4263x; 3.2916x over previous
//
#include <hip/hip_runtime.h>
#include <math.h>

#define EMB 1024
#define HEADS 16
#define HDIM 64
#define NBATCH 4
#define SEQ 2048
#define ROWS (NBATCH * SEQ)   // 8192
#define SCALE 0.125f          // 64^-0.5

typedef float f32x4 __attribute__((ext_vector_type(4)));
typedef short bf16x8 __attribute__((ext_vector_type(8)));

__device__ inline unsigned short f2bf(float f) {
    unsigned int u = __builtin_bit_cast(unsigned int, f);
    u += 0x7fffu + ((u >> 16) & 1u);   // round-to-nearest-even
    return (unsigned short)(u >> 16);
}

// ---------------- LayerNorm -> bf16 h ----------------
__global__ __launch_bounds__(256) void ln_kernel(const float* __restrict__ x,
                                                 const float* __restrict__ w,
                                                 const float* __restrict__ b,
                                                 unsigned short* __restrict__ h) {
    int row = blockIdx.x;
    const float* xr = x + (size_t)row * EMB;
    unsigned short* hr = h + (size_t)row * EMB;
    float4 v = ((const float4*)xr)[threadIdx.x];
    float s  = v.x + v.y + v.z + v.w;
    float ss = v.x*v.x + v.y*v.y + v.z*v.z + v.w*v.w;
    #pragma unroll
    for (int o = 32; o; o >>= 1) { s += __shfl_xor(s, o); ss += __shfl_xor(ss, o); }
    __shared__ float red[8];
    int wid = threadIdx.x >> 6;
    if ((threadIdx.x & 63) == 0) { red[wid] = s; red[4 + wid] = ss; }
    __syncthreads();
    if (threadIdx.x == 0) {
        red[0] = red[0] + red[1] + red[2] + red[3];
        red[4] = red[4] + red[5] + red[6] + red[7];
    }
    __syncthreads();
    float mu  = red[0] * (1.f / EMB);
    float var = red[4] * (1.f / EMB) - mu * mu;
    float rstd = rsqrtf(var + 1e-5f);
    float4 wv = ((const float4*)w)[threadIdx.x];
    float4 bv = ((const float4*)b)[threadIdx.x];
    ushort4 o;
    o.x = f2bf((v.x - mu) * rstd * wv.x + bv.x);
    o.y = f2bf((v.y - mu) * rstd * wv.y + bv.y);
    o.z = f2bf((v.z - mu) * rstd * wv.z + bv.z);
    o.w = f2bf((v.w - mu) * rstd * wv.w + bv.w);
    ((ushort4*)hr)[threadIdx.x] = o;
}

// ---------------- transpose + f32->bf16: WT[n][k] = bf16(W[k][n]), K=1024 ----------------
__global__ __launch_bounds__(256) void wconv(const float* __restrict__ W,
                                             unsigned short* __restrict__ WT, int N) {
    __shared__ float t[32][33];
    int k0 = blockIdx.x * 32, n0 = blockIdx.y * 32;
    int tx = threadIdx.x & 31, ty = threadIdx.x >> 5;   // ty 0..7
    #pragma unroll
    for (int i = 0; i < 32; i += 8)
        t[ty + i][tx] = W[(size_t)(k0 + ty + i) * N + n0 + tx];
    __syncthreads();
    #pragma unroll
    for (int i = 0; i < 32; i += 8)
        WT[(size_t)(n0 + ty + i) * EMB + k0 + tx] = f2bf(t[tx][ty + i]);
}

// ---------------- QKV GEMM bf16 MFMA: h[8192,1024] @ wT[3072,1024]^T + bias ----------------
// 128x128 tile, BK=32, 4 waves (2x2), each wave 64x64 (4x4 fragments of 16x16x32).
__global__ __launch_bounds__(256) void qkv_mfma(const unsigned short* __restrict__ A,
                                                const unsigned short* __restrict__ BT,
                                                const float* __restrict__ bias,
                                                unsigned short* __restrict__ qo,
                                                unsigned short* __restrict__ ko,
                                                unsigned short* __restrict__ vo) {
    __shared__ unsigned short As[128][40];
    __shared__ unsigned short Bs[128][40];
    int tid = threadIdx.x;
    int w = tid >> 6, lane = tid & 63, lg = lane >> 4, lr = lane & 15;
    int wr = w >> 1, wc = w & 1;
    int bm = blockIdx.y, bn = blockIdx.x;
    int srow = tid >> 2;            // 0..63
    int scol = (tid & 3) * 8;       // 0,8,16,24 (k within BK)
    const unsigned short* Ap = A + (size_t)(bm * 128 + srow) * EMB + scol;
    const unsigned short* Bp = BT + (size_t)(bn * 128 + srow) * EMB + scol;
    f32x4 acc[4][4];
    #pragma unroll
    for (int m = 0; m < 4; ++m)
        #pragma unroll
        for (int n = 0; n < 4; ++n) acc[m][n] = (f32x4){0.f, 0.f, 0.f, 0.f};
    for (int k0 = 0; k0 < EMB; k0 += 32) {
        bf16x8 a0 = *(const bf16x8*)(Ap + k0);
        bf16x8 a1 = *(const bf16x8*)(Ap + (size_t)64 * EMB + k0);
        bf16x8 b0 = *(const bf16x8*)(Bp + k0);
        bf16x8 b1 = *(const bf16x8*)(Bp + (size_t)64 * EMB + k0);
        __syncthreads();
        *(bf16x8*)&As[srow][scol] = a0;
        *(bf16x8*)&As[64 + srow][scol] = a1;
        *(bf16x8*)&Bs[srow][scol] = b0;
        *(bf16x8*)&Bs[64 + srow][scol] = b1;
        __syncthreads();
        bf16x8 af[4], bf[4];
        #pragma unroll
        for (int m = 0; m < 4; ++m) af[m] = *(const bf16x8*)&As[wr * 64 + m * 16 + lr][lg * 8];
        #pragma unroll
        for (int n = 0; n < 4; ++n) bf[n] = *(const bf16x8*)&Bs[wc * 64 + n * 16 + lr][lg * 8];
        #pragma unroll
        for (int m = 0; m < 4; ++m)
            #pragma unroll
            for (int n = 0; n < 4; ++n)
                acc[m][n] = __builtin_amdgcn_mfma_f32_16x16x32_bf16(af[m], bf[n], acc[m][n], 0, 0, 0);
    }
    // epilogue: bias, de-interleave qkv (c%3), q/k:[b][h][n][d], v:[b][h][d][n]
    #pragma unroll
    for (int n = 0; n < 4; ++n) {
        int c = bn * 128 + wc * 64 + n * 16 + lr;
        int head = c / 192;
        int rem = c - head * 192;
        int d = rem / 3;
        int which = rem - d * 3;
        float bv = bias[c];
        #pragma unroll
        for (int m = 0; m < 4; ++m) {
            #pragma unroll
            for (int r = 0; r < 4; ++r) {
                int row = bm * 128 + wr * 64 + m * 16 + lg * 4 + r;
                int bb = row >> 11;
                int nq = row & 2047;
                unsigned short hv = f2bf(acc[m][n][r] + bv);
                if (which == 0)
                    qo[(((size_t)bb * HEADS + head) * SEQ + nq) * HDIM + d] = hv;
                else if (which == 1)
                    ko[(((size_t)bb * HEADS + head) * SEQ + nq) * HDIM + d] = hv;
                else
                    vo[(((size_t)bb * HEADS + head) * HDIM + d) * SEQ + nq] = hv;
            }
        }
    }
}

// ---------------- Flash attention, bf16 MFMA (unchanged math; bf16 output) ----------------
__global__ __launch_bounds__(256) void attn_mfma(const unsigned short* __restrict__ Q,
                                                 const unsigned short* __restrict__ K,
                                                 const unsigned short* __restrict__ VT,
                                                 unsigned short* __restrict__ AO) {
    __shared__ unsigned short ks[64][72];
    __shared__ unsigned short vt[64][72];
    __shared__ unsigned short ps[4][16][72];
    int tid = threadIdx.x;
    int w = tid >> 6, lane = tid & 63;
    int lg = lane >> 4, lr = lane & 15;
    int b = blockIdx.z, hh = blockIdx.y;
    int q0 = blockIdx.x * 64;
    size_t bh = ((size_t)b * HEADS + hh) * (size_t)SEQ * HDIM;
    const unsigned short* qg = Q + bh + (size_t)(q0 + w * 16 + lr) * HDIM + 8 * lg;
    bf16x8 qf0 = *(const bf16x8*)qg;
    bf16x8 qf1 = *(const bf16x8*)(qg + 32);
    f32x4 o[4];
    #pragma unroll
    for (int dt = 0; dt < 4; ++dt) o[dt] = (f32x4){0.f, 0.f, 0.f, 0.f};
    float m[4] = {-INFINITY, -INFINITY, -INFINITY, -INFINITY};
    float l[4] = {0.f, 0.f, 0.f, 0.f};
    const unsigned short* kg = K + bh;
    const unsigned short* vg = VT + bh;
    int sr = tid >> 2;
    int sc = (tid & 3) << 4;
    for (int kb = 0; kb < SEQ / 64; ++kb) {
        __syncthreads();
        const unsigned short* kp = kg + (size_t)(kb * 64 + sr) * HDIM + sc;
        *(float4*)&ks[sr][sc]     = *(const float4*)kp;
        *(float4*)&ks[sr][sc + 8] = *(const float4*)(kp + 8);
        const unsigned short* vp = vg + (size_t)sr * SEQ + kb * 64 + sc;
        *(float4*)&vt[sr][sc]     = *(const float4*)vp;
        *(float4*)&vt[sr][sc + 8] = *(const float4*)(vp + 8);
        __syncthreads();
        f32x4 s[4];
        #pragma unroll
        for (int kn = 0; kn < 4; ++kn) {
            bf16x8 kf0 = *(const bf16x8*)&ks[kn * 16 + lr][8 * lg];
            bf16x8 kf1 = *(const bf16x8*)&ks[kn * 16 + lr][32 + 8 * lg];
            f32x4 acc = (f32x4){0.f, 0.f, 0.f, 0.f};
            acc = __builtin_amdgcn_mfma_f32_16x16x32_bf16(qf0, kf0, acc, 0, 0, 0);
            acc = __builtin_amdgcn_mfma_f32_16x16x32_bf16(qf1, kf1, acc, 0, 0, 0);
            s[kn] = acc;
        }
        #pragma unroll
        for (int r = 0; r < 4; ++r) {
            float s0 = s[0][r] * SCALE, s1 = s[1][r] * SCALE;
            float s2 = s[2][r] * SCALE, s3 = s[3][r] * SCALE;
            float mr = fmaxf(fmaxf(s0, s1), fmaxf(s2, s3));
            mr = fmaxf(mr, __shfl_xor(mr, 1));
            mr = fmaxf(mr, __shfl_xor(mr, 2));
            mr = fmaxf(mr, __shfl_xor(mr, 4));
            mr = fmaxf(mr, __shfl_xor(mr, 8));
            float mn = fmaxf(m[r], mr);
            float cr = __expf(m[r] - mn);
            float p0 = __expf(s0 - mn), p1 = __expf(s1 - mn);
            float p2 = __expf(s2 - mn), p3 = __expf(s3 - mn);
            float ls = p0 + p1 + p2 + p3;
            ls += __shfl_xor(ls, 1);
            ls += __shfl_xor(ls, 2);
            ls += __shfl_xor(ls, 4);
            ls += __shfl_xor(ls, 8);
            l[r] = l[r] * cr + ls;
            m[r] = mn;
            int q = lg * 4 + r;
            ps[w][q][lr]      = f2bf(p0);
            ps[w][q][lr + 16] = f2bf(p1);
            ps[w][q][lr + 32] = f2bf(p2);
            ps[w][q][lr + 48] = f2bf(p3);
            #pragma unroll
            for (int dt = 0; dt < 4; ++dt) o[dt][r] *= cr;
        }
        bf16x8 pa0 = *(const bf16x8*)&ps[w][lr][8 * lg];
        bf16x8 pa1 = *(const bf16x8*)&ps[w][lr][32 + 8 * lg];
        #pragma unroll
        for (int dt = 0; dt < 4; ++dt) {
            bf16x8 vf0 = *(const bf16x8*)&vt[dt * 16 + lr][8 * lg];
            bf16x8 vf1 = *(const bf16x8*)&vt[dt * 16 + lr][32 + 8 * lg];
            o[dt] = __builtin_amdgcn_mfma_f32_16x16x32_bf16(pa0, vf0, o[dt], 0, 0, 0);
            o[dt] = __builtin_amdgcn_mfma_f32_16x16x32_bf16(pa1, vf1, o[dt], 0, 0, 0);
        }
    }
    #pragma unroll
    for (int r = 0; r < 4; ++r) {
        float inv = 1.f / l[r];
        int q = q0 + w * 16 + lg * 4 + r;
        unsigned short* op = AO + ((size_t)b * SEQ + q) * EMB + hh * HDIM + lr;
        #pragma unroll
        for (int dt = 0; dt < 4; ++dt) op[dt * 16] = f2bf(o[dt][r] * inv);
    }
}

// ---------------- Proj GEMM bf16 MFMA + bias + residual -> f32 out ----------------
__global__ __launch_bounds__(256) void proj_mfma(const unsigned short* __restrict__ A,
                                                 const unsigned short* __restrict__ BT,
                                                 const float* __restrict__ bias,
                                                 const float* __restrict__ resid,
                                                 float* __restrict__ out) {
    __shared__ unsigned short As[128][40];
    __shared__ unsigned short Bs[128][40];
    int tid = threadIdx.x;
    int w = tid >> 6, lane = tid & 63, lg = lane >> 4, lr = lane & 15;
    int wr = w >> 1, wc = w & 1;
    int bm = blockIdx.y, bn = blockIdx.x;
    int srow = tid >> 2;
    int scol = (tid & 3) * 8;
    const unsigned short* Ap = A + (size_t)(bm * 128 + srow) * EMB + scol;
    const unsigned short* Bp = BT + (size_t)(bn * 128 + srow) * EMB + scol;
    f32x4 acc[4][4];
    #pragma unroll
    for (int m = 0; m < 4; ++m)
        #pragma unroll
        for (int n = 0; n < 4; ++n) acc[m][n] = (f32x4){0.f, 0.f, 0.f, 0.f};
    for (int k0 = 0; k0 < EMB; k0 += 32) {
        bf16x8 a0 = *(const bf16x8*)(Ap + k0);
        bf16x8 a1 = *(const bf16x8*)(Ap + (size_t)64 * EMB + k0);
        bf16x8 b0 = *(const bf16x8*)(Bp + k0);
        bf16x8 b1 = *(const bf16x8*)(Bp + (size_t)64 * EMB + k0);
        __syncthreads();
        *(bf16x8*)&As[srow][scol] = a0;
        *(bf16x8*)&As[64 + srow][scol] = a1;
        *(bf16x8*)&Bs[srow][scol] = b0;
        *(bf16x8*)&Bs[64 + srow][scol] = b1;
        __syncthreads();
        bf16x8 af[4], bf[4];
        #pragma unroll
        for (int m = 0; m < 4; ++m) af[m] = *(const bf16x8*)&As[wr * 64 + m * 16 + lr][lg * 8];
        #pragma unroll
        for (int n = 0; n < 4; ++n) bf[n] = *(const bf16x8*)&Bs[wc * 64 + n * 16 + lr][lg * 8];
        #pragma unroll
        for (int m = 0; m < 4; ++m)
            #pragma unroll
            for (int n = 0; n < 4; ++n)
                acc[m][n] = __builtin_amdgcn_mfma_f32_16x16x32_bf16(af[m], bf[n], acc[m][n], 0, 0, 0);
    }
    #pragma unroll
    for (int n = 0; n < 4; ++n) {
        int c = bn * 128 + wc * 64 + n * 16 + lr;
        float bv = bias[c];
        #pragma unroll
        for (int m = 0; m < 4; ++m) {
            #pragma unroll
            for (int r = 0; r < 4; ++r) {
                size_t row = (size_t)bm * 128 + wr * 64 + m * 16 + lg * 4 + r;
                out[row * EMB + c] = acc[m][n][r] + bv + resid[row * EMB + c];
            }
        }
    }
}

extern "C" void kernel_launch(void* const* d_in, const int* in_sizes, int n_in,
                              void* d_out, int out_size, void* d_ws, size_t ws_size,
                              hipStream_t stream) {
    const float* x      = (const float*)d_in[0];
    const float* ln_w   = (const float*)d_in[1];
    const float* ln_b   = (const float*)d_in[2];
    const float* w_qkv  = (const float*)d_in[3];
    const float* b_qkv  = (const float*)d_in[4];
    const float* w_proj = (const float*)d_in[5];
    const float* b_proj = (const float*)d_in[6];
    float* out = (float*)d_out;

    char* ws = (char*)d_ws;
    const size_t MB16 = (size_t)ROWS * EMB * sizeof(unsigned short); // 16 MiB
    unsigned short* h   = (unsigned short*)ws;                // LN out (bf16)
    unsigned short* q   = (unsigned short*)(ws + MB16);
    unsigned short* k   = (unsigned short*)(ws + 2 * MB16);
    unsigned short* v   = (unsigned short*)(ws + 3 * MB16);   // [b][h][d][n]
    unsigned short* ao  = (unsigned short*)(ws + 4 * MB16);   // attn out (bf16)
    unsigned short* wqT = (unsigned short*)(ws + 5 * MB16);   // [3072][1024]
    unsigned short* wpT = (unsigned short*)(ws + 5 * MB16 + (size_t)3 * EMB * EMB * 2);

    wconv<<<dim3(EMB / 32, 3 * EMB / 32), 256, 0, stream>>>(w_qkv, wqT, 3 * EMB);
    wconv<<<dim3(EMB / 32, EMB / 32), 256, 0, stream>>>(w_proj, wpT, EMB);
    ln_kernel<<<ROWS, 256, 0, stream>>>(x, ln_w, ln_b, h);
    qkv_mfma<<<dim3(3 * EMB / 128, ROWS / 128), 256, 0, stream>>>(h, wqT, b_qkv, q, k, v);
    attn_mfma<<<dim3(SEQ / 64, HEADS, NBATCH), 256, 0, stream>>>(q, k, v, ao);
    proj_mfma<<<dim3(EMB / 128, ROWS / 128), 256, 0, stream>>>(ao, wpT, b_proj, x, out);
}